// Round 1
// baseline (118.069 us; speedup 1.0000x reference)
//
#include <hip/hip_runtime.h>
#include <math.h>

// ws layout: [0,8) double accumulator; [16, 16+16*n_pts) packed float4 point table
// pts[p] = (z0x, z0y, v0x, v0y)

__global__ void pack_init_kernel(const float* __restrict__ z0,
                                 const float* __restrict__ v0,
                                 float4* __restrict__ pts,
                                 double* __restrict__ acc, int n_pts) {
    int p = blockIdx.x * blockDim.x + threadIdx.x;
    if (p < n_pts) {
        pts[p] = make_float4(z0[2 * p], z0[2 * p + 1], v0[2 * p], v0[2 * p + 1]);
    }
    if (p == 0) *acc = 0.0;
}

__global__ __launch_bounds__(256) void cvm_main_kernel(
    const int2* __restrict__ idx, const float* __restrict__ t,
    const float4* __restrict__ pts,
    const float* __restrict__ t0p, const float* __restrict__ tnp,
    const float* __restrict__ betap,
    int n_events, int n_pts, double* __restrict__ acc) {

    const float b  = betap[0];
    const float t0 = t0p[0];
    const float tn = tnp[0];
    const int tid = blockIdx.x * blockDim.x + threadIdx.x;
    const int nthreads = gridDim.x * blockDim.x;

    // Accumulates Sum(d_event) + Sum(integral); final = N*b - this.
    float local = 0.0f;

    // ---- Event part: grid-stride over events, float4 gathers (L1/L2-hot 80KB table)
    for (int e = tid; e < n_events; e += nthreads) {
        int2 ij  = idx[e];
        float te = t[e];
        float4 pi = pts[ij.x];
        float4 pj = pts[ij.y];
        float dx = (pi.x - pj.x) + (pi.z - pj.z) * te;
        float dy = (pi.y - pj.y) + (pi.w - pj.w) * te;
        local += dx * dx + dy * dy;
    }

    // ---- Pair part: block-strided rows i, thread-strided columns j>i
    const float sqrt_pi_over_2 = 0.88622692545275801365f;  // sqrt(pi)/2
    for (int i = blockIdx.x; i < n_pts - 1; i += gridDim.x) {
        float4 pi = pts[i];
        for (int j = i + 1 + threadIdx.x; j < n_pts; j += blockDim.x) {
            float4 pj = pts[j];
            float dzx = pi.x - pj.x, dzy = pi.y - pj.y;
            float dvx = pi.z - pj.z, dvy = pi.w - pj.w;
            float a2 = dzx * dzx + dzy * dzy;
            float b2 = dvx * dvx + dvy * dvy;
            float ab = dzx * dvx + dzy * dvy;
            float bnorm = sqrtf(b2);
            float mu = ab / b2;
            float pref = expf(b - a2 + ab * mu) * (sqrt_pi_over_2 / bnorm);
            float integral =
                pref * (erff(bnorm * (tn + mu)) - erff(bnorm * (t0 + mu)));
            local += integral;
        }
    }

    // ---- Reduce: wave64 shuffle in double, LDS across 4 waves, one atomic/block
    double v = (double)local;
    #pragma unroll
    for (int off = 32; off > 0; off >>= 1) v += __shfl_down(v, off, 64);

    __shared__ double wsum[4];
    int lane = threadIdx.x & 63;
    int w = threadIdx.x >> 6;
    if (lane == 0) wsum[w] = v;
    __syncthreads();
    if (threadIdx.x == 0) {
        double s = wsum[0] + wsum[1] + wsum[2] + wsum[3];
        atomicAdd(acc, s);
    }
}

__global__ void finish_kernel(const float* __restrict__ betap,
                              const double* __restrict__ acc,
                              float* __restrict__ out, int n_events) {
    out[0] = (float)((double)n_events * (double)betap[0] - *acc);
}

extern "C" void kernel_launch(void* const* d_in, const int* in_sizes, int n_in,
                              void* d_out, int out_size, void* d_ws, size_t ws_size,
                              hipStream_t stream) {
    const int2*  idx  = (const int2*)d_in[0];
    const float* t    = (const float*)d_in[1];
    const float* t0   = (const float*)d_in[2];
    const float* tn   = (const float*)d_in[3];
    const float* z0   = (const float*)d_in[4];
    const float* v0   = (const float*)d_in[5];
    const float* beta = (const float*)d_in[6];
    const int n_events = in_sizes[1];
    const int n_pts    = in_sizes[4] / 2;

    double* acc = (double*)d_ws;
    float4* pts = (float4*)((char*)d_ws + 16);

    pack_init_kernel<<<(n_pts + 255) / 256, 256, 0, stream>>>(z0, v0, pts, acc, n_pts);
    cvm_main_kernel<<<1280, 256, 0, stream>>>(idx, t, pts, t0, tn, beta,
                                              n_events, n_pts, acc);
    finish_kernel<<<1, 1, 0, stream>>>(beta, acc, (float*)d_out, n_events);
}

// Round 2
// 102.328 us; speedup vs baseline: 1.1538x; 1.1538x over previous
//
#include <hip/hip_runtime.h>
#include <math.h>

// ws layout: [0, NBLK*8) double partials; [32768, 32768+16*n_pts) float4 pts
// pts[p] = (z0x, z0y, v0x, v0y)

#define NBLK 4096
#define NTHR 256

__global__ void pack_kernel(const float* __restrict__ z0,
                            const float* __restrict__ v0,
                            float4* __restrict__ pts, int n_pts) {
    int p = blockIdx.x * blockDim.x + threadIdx.x;
    if (p < n_pts)
        pts[p] = make_float4(z0[2 * p], z0[2 * p + 1], v0[2 * p], v0[2 * p + 1]);
}

__device__ __forceinline__ float fast_exp(float x) {
    return __builtin_amdgcn_exp2f(x * 1.4426950408889634f);  // exp(x)=2^(x·log2e)
}

// Abramowitz-Stegun 7.1.26, |err| <= 1.5e-7 absolute. 1 rcp + 1 exp + 7 fma.
__device__ __forceinline__ float fast_erf(float x) {
    float ax = fabsf(x);
    float t = __builtin_amdgcn_rcpf(fmaf(0.3275911f, ax, 1.0f));
    float p = fmaf(t, fmaf(t, fmaf(t, fmaf(t, 1.061405429f, -1.453152027f),
                                   1.421413741f), -0.284496736f), 0.254829592f);
    float y = fmaf(-(p * t), fast_exp(-ax * ax), 1.0f);
    return copysignf(y, x);
}

__global__ __launch_bounds__(256) void cvm_main_kernel(
    const int2* __restrict__ idx, const float* __restrict__ t,
    const float4* __restrict__ pts,
    const float* __restrict__ t0p, const float* __restrict__ tnp,
    const float* __restrict__ betap,
    int n_events, int n_pts, double* __restrict__ partials) {

    const float b  = betap[0];
    const float t0 = t0p[0];
    const float tn = tnp[0];
    const int tid = blockIdx.x * blockDim.x + threadIdx.x;
    const int nthreads = gridDim.x * blockDim.x;

    // Accumulates Sum(d_event) + Sum(integral); final = N*b - this.
    float local = 0.0f;

    // ---- Event part: grid-stride, coalesced idx/t, float4 gathers (L1/L2-hot)
    for (int e = tid; e < n_events; e += nthreads) {
        int2 ij  = idx[e];
        float te = t[e];
        float4 pi = pts[ij.x];
        float4 pj = pts[ij.y];
        float dx = (pi.x - pj.x) + (pi.z - pj.z) * te;
        float dy = (pi.y - pj.y) + (pi.w - pj.w) * te;
        local = fmaf(dx, dx, fmaf(dy, dy, local));
    }

    // ---- Pair part: equal flat-index chunks per wave; lane L handles
    // k = wave_base + L + 64*m, so pts[j] loads are lane-consecutive (coalesced).
    const long long P = (long long)n_pts * (n_pts - 1) / 2;
    const int n_waves = nthreads >> 6;
    const int wave = tid >> 6;
    const int lane = threadIdx.x & 63;
    const long long per = (P + n_waves - 1) / n_waves;
    const long long kend = min((long long)(wave + 1) * per, P);
    long long k = (long long)wave * per + lane;

    const float spi2 = 0.88622692545275801365f;  // sqrt(pi)/2
    if (k < kend) {
        // decode flat k -> (i,j): C(i) = i*(2n-1-i)/2 pairs precede row i
        double nn = 2.0 * n_pts - 1.0;
        int i = (int)((nn - sqrt(fmax(nn * nn - 8.0 * (double)k, 0.0))) * 0.5);
        if (i < 0) i = 0;
        if (i > n_pts - 2) i = n_pts - 2;
        while ((long long)(i + 1) * (2LL * n_pts - i - 2) / 2 <= k) ++i;
        while ((long long)i * (2LL * n_pts - i - 1) / 2 > k) --i;
        int j = i + 1 + (int)(k - (long long)i * (2LL * n_pts - i - 1) / 2);

        float4 pi = pts[i];
        while (true) {
            float4 pj = pts[j];
            float dzx = pi.x - pj.x, dzy = pi.y - pj.y;
            float dvx = pi.z - pj.z, dvy = pi.w - pj.w;
            float a2 = fmaf(dzx, dzx, dzy * dzy);
            float b2 = fmaf(dvx, dvx, dvy * dvy);
            float ab = fmaf(dzx, dvx, dzy * dvy);
            float r   = __builtin_amdgcn_rsqf(b2);  // 1/bnorm
            float rb2 = r * r;                      // 1/b2
            float mu  = ab * rb2;
            float e   = b - a2 + ab * mu;           // <= b by Cauchy-Schwarz
            float pref = fast_exp(e) * (spi2 * r);
            float bnorm = b2 * r;
            float x1 = bnorm * (tn + mu);
            float x0 = bnorm * (t0 + mu);
            local = fmaf(pref, fast_erf(x1) - fast_erf(x0), local);

            k += 64;
            if (k >= kend) break;
            j += 64;
            if (j >= n_pts) {  // row rollover (rare: row len ~2500+, stride 64)
                do { int over = j - n_pts; ++i; j = i + 1 + over; } while (j >= n_pts);
                pi = pts[i];
            }
        }
    }

    // ---- Block reduce (double), plain store — no atomics
    double v = (double)local;
    #pragma unroll
    for (int off = 32; off > 0; off >>= 1) v += __shfl_down(v, off, 64);
    __shared__ double wsum[4];
    if ((threadIdx.x & 63) == 0) wsum[threadIdx.x >> 6] = v;
    __syncthreads();
    if (threadIdx.x == 0)
        partials[blockIdx.x] = wsum[0] + wsum[1] + wsum[2] + wsum[3];
}

__global__ void finish_kernel(const double* __restrict__ partials, int nblk,
                              const float* __restrict__ betap,
                              float* __restrict__ out, int n_events) {
    double v = 0.0;
    for (int i = threadIdx.x; i < nblk; i += blockDim.x) v += partials[i];
    #pragma unroll
    for (int off = 32; off > 0; off >>= 1) v += __shfl_down(v, off, 64);
    __shared__ double wsum[4];
    if ((threadIdx.x & 63) == 0) wsum[threadIdx.x >> 6] = v;
    __syncthreads();
    if (threadIdx.x == 0)
        out[0] = (float)((double)n_events * (double)betap[0] -
                         (wsum[0] + wsum[1] + wsum[2] + wsum[3]));
}

extern "C" void kernel_launch(void* const* d_in, const int* in_sizes, int n_in,
                              void* d_out, int out_size, void* d_ws, size_t ws_size,
                              hipStream_t stream) {
    const int2*  idx  = (const int2*)d_in[0];
    const float* t    = (const float*)d_in[1];
    const float* t0   = (const float*)d_in[2];
    const float* tn   = (const float*)d_in[3];
    const float* z0   = (const float*)d_in[4];
    const float* v0   = (const float*)d_in[5];
    const float* beta = (const float*)d_in[6];
    const int n_events = in_sizes[1];
    const int n_pts    = in_sizes[4] / 2;

    double* partials = (double*)d_ws;
    float4* pts = (float4*)((char*)d_ws + NBLK * sizeof(double));

    pack_kernel<<<(n_pts + NTHR - 1) / NTHR, NTHR, 0, stream>>>(z0, v0, pts, n_pts);
    cvm_main_kernel<<<NBLK, NTHR, 0, stream>>>(idx, t, pts, t0, tn, beta,
                                               n_events, n_pts, partials);
    finish_kernel<<<1, NTHR, 0, stream>>>(partials, NBLK, beta,
                                          (float*)d_out, n_events);
}